// Round 1
// baseline (6118.002 us; speedup 1.0000x reference)
//
#include <hip/hip_runtime.h>

#define Bb 128
#define Nn 512
#define Ff 16
#define Hh 128
#define HIST 24
#define FW 24
#define Ee 8192
#define BN (Bb*Nn)      // 65536
#define NE (Bb*Ee)      // 1048576
#define THIST (HIST+FW) // 48
#define GM 16           // nodes per GRU block

__global__ __launch_bounds__(256) void k_deg(const int* __restrict__ dst, float* __restrict__ deg){
  int e = blockIdx.x*256 + threadIdx.x;
  if (e < NE) atomicAdd(&deg[dst[e]], 1.0f);
}

__global__ __launch_bounds__(256) void k_invdeg(float* deg){
  int n = blockIdx.x*256 + threadIdx.x;
  if (n < BN) deg[n] = 1.0f / fmaxf(deg[n], 1.0f);
}

__global__ __launch_bounds__(256) void k_init_xn(const float* __restrict__ pm, float* __restrict__ xn){
  int g = blockIdx.x*256 + threadIdx.x;
  if (g < BN){ int b = g>>9, n = g&511; xn[g] = pm[((size_t)b*HIST + (HIST-1))*Nn + n]; }
}

__global__ __launch_bounds__(256) void k_transpose(const float* __restrict__ W_ih, const float* __restrict__ W_hh,
                                                   float* __restrict__ Wt_ih, float* __restrict__ Wt_hh){
  int i = blockIdx.x*256 + threadIdx.x;
  if (i < 384*128){ int j = i>>7, k = i&127; Wt_hh[k*384 + j] = W_hh[i]; }
  if (i < 384*18){ int j = i/18, c = i - j*18; Wt_ih[c*384 + j] = W_ih[i]; }
}

// sfeat[t][g] = feat_t[g]·W_nb[1:17], rootf[t][g] = feat_t[g]·W_root[1:17]
__global__ __launch_bounds__(256) void k_sfeat(const float* __restrict__ feature, const float* __restrict__ W_nb,
                                               const float* __restrict__ W_root,
                                               float* __restrict__ sfeat, float* __restrict__ rootf){
  int idx = blockIdx.x*256 + threadIdx.x;
  if (idx >= FW*BN) return;
  int t = idx >> 16, g = idx & 0xFFFF;
  int b = g>>9, n = g&511;
  const float* f = feature + (((size_t)b*THIST + HIST + t)*Nn + n)*Ff;
  float s = 0.f, r = 0.f;
  #pragma unroll
  for (int k = 0; k < Ff; k++){ float v = f[k]; s = fmaf(v, W_nb[1+k], s); r = fmaf(v, W_root[1+k], r); }
  sfeat[idx] = s; rootf[idx] = r;
}

// SF[t][d] += sfeat[t][src] over all edges, all t (parallel over edges)
__global__ __launch_bounds__(256) void k_aggF(const int* __restrict__ src, const int* __restrict__ dst,
                                              const float* __restrict__ sfeat, float* __restrict__ SF){
  int e = blockIdx.x*256 + threadIdx.x;
  if (e >= NE) return;
  int s = src[e], d = dst[e];
  #pragma unroll 1
  for (int t = 0; t < FW; t++) atomicAdd(&SF[t*BN + d], sfeat[t*BN + s]);
}

// SX[d] += xn[src] (scalar dynamic aggregation, per step)
__global__ __launch_bounds__(256) void k_sx(const int* __restrict__ src, const int* __restrict__ dst,
                                            const float* __restrict__ xn, float* __restrict__ SX){
  int e = blockIdx.x*256 + threadIdx.x;
  if (e < NE) atomicAdd(&SX[dst[e]], xn[src[e]]);
}

// Fused GCN-gate + GRU cell + readout. 128 threads, GM nodes per block.
// Thread j owns gate rows j (r), j+128 (z), j+256 (n) and h_new[j].
__global__ __launch_bounds__(128) void k_gru(
    float* __restrict__ h, float* __restrict__ xn,
    const float* __restrict__ SX, const float* __restrict__ SF_t,
    const float* __restrict__ rootf_t, const float* __restrict__ invdeg,
    const float* __restrict__ feature,
    const float* __restrict__ Wt_hh, const float* __restrict__ Wt_ih,
    const float* __restrict__ b_ih, const float* __restrict__ b_hh,
    const float* __restrict__ W_nb, const float* __restrict__ b_nb,
    const float* __restrict__ W_root, const float* __restrict__ W_out,
    const float* __restrict__ b_out, float* __restrict__ out, int t)
{
  __shared__ float h_lds[GM][Hh];
  __shared__ float x2_lds[GM][18];
  __shared__ float red[2][GM];
  const int tid = threadIdx.x;     // 0..127
  const int g0 = blockIdx.x * GM;  // GM | 512 -> whole block same batch b

  #pragma unroll
  for (int m = 0; m < GM; m++) h_lds[m][tid] = h[(size_t)(g0+m)*Hh + tid];

  {
    int b = g0 >> 9, n0 = g0 & 511;
    const float* fb = feature + (((size_t)b*THIST + HIST + t)*Nn + n0)*Ff;
    for (int i = tid; i < GM*Ff; i += 128){
      int m = i >> 4, k = i & 15;
      x2_lds[m][1+k] = fb[i];  // node n0+m, feature k (contiguous)
    }
  }
  if (tid < GM){
    int g = g0 + tid;
    float xv = xn[g];
    float pre = invdeg[g]*(W_nb[0]*SX[g] + SF_t[g]) + b_nb[0] + W_root[0]*xv + rootf_t[g];
    x2_lds[tid][0]  = xv;
    x2_lds[tid][17] = 1.f/(1.f + expf(-pre));  // gcn
  }
  __syncthreads();

  float accR[GM], accZ[GM], accIN[GM], accHN[GM];
  {
    float bR = b_ih[tid] + b_hh[tid];
    float bZ = b_ih[128+tid] + b_hh[128+tid];
    float bI = b_ih[256+tid];
    float bH = b_hh[256+tid];
    #pragma unroll
    for (int m = 0; m < GM; m++){ accR[m]=bR; accZ[m]=bZ; accIN[m]=bI; accHN[m]=bH; }
  }

  // gh = W_hh @ h  (K=128, register-tiled over GM nodes, float4 LDS broadcast)
  for (int k = 0; k < Hh; k += 4){
    float wr[4], wz[4], wn[4];
    #pragma unroll
    for (int u = 0; u < 4; u++){
      const float* wp = Wt_hh + (size_t)(k+u)*384 + tid;
      wr[u] = wp[0]; wz[u] = wp[128]; wn[u] = wp[256];
    }
    #pragma unroll
    for (int m = 0; m < GM; m++){
      const float4 hv = *(const float4*)&h_lds[m][k];
      accR[m]  = fmaf(wr[3],hv.w, fmaf(wr[2],hv.z, fmaf(wr[1],hv.y, fmaf(wr[0],hv.x, accR[m]))));
      accZ[m]  = fmaf(wz[3],hv.w, fmaf(wz[2],hv.z, fmaf(wz[1],hv.y, fmaf(wz[0],hv.x, accZ[m]))));
      accHN[m] = fmaf(wn[3],hv.w, fmaf(wn[2],hv.z, fmaf(wn[1],hv.y, fmaf(wn[0],hv.x, accHN[m]))));
    }
  }

  // gi = W_ih @ [xn, feat16, gcn]  (K=18)
  #pragma unroll
  for (int c = 0; c < 18; c++){
    const float* wp = Wt_ih + (size_t)c*384 + tid;
    float wr = wp[0], wz = wp[128], wn = wp[256];
    #pragma unroll
    for (int m = 0; m < GM; m++){
      float xv = x2_lds[m][c];
      accR[m] = fmaf(wr, xv, accR[m]);
      accZ[m] = fmaf(wz, xv, accZ[m]);
      accIN[m] = fmaf(wn, xv, accIN[m]);
    }
  }

  const float wout = W_out[tid];
  float pout[GM];
  #pragma unroll
  for (int m = 0; m < GM; m++){
    float r  = 1.f/(1.f + expf(-accR[m]));
    float z  = 1.f/(1.f + expf(-accZ[m]));
    float nn = tanhf(fmaf(r, accHN[m], accIN[m]));
    float hold = h_lds[m][tid];
    float hv = (1.f - z)*nn + z*hold;
    h[(size_t)(g0+m)*Hh + tid] = hv;
    pout[m] = hv * wout;
  }

  // xn_new[m] = sum_j h_new[m][j]*wout[j] + b_out  (reduce over 128 threads)
  int lane = tid & 63, wv = tid >> 6;
  #pragma unroll
  for (int m = 0; m < GM; m++){
    float v = pout[m];
    v += __shfl_down(v, 32); v += __shfl_down(v, 16); v += __shfl_down(v, 8);
    v += __shfl_down(v, 4);  v += __shfl_down(v, 2);  v += __shfl_down(v, 1);
    if (lane == 0) red[wv][m] = v;
  }
  __syncthreads();
  if (tid < GM){
    int g = g0 + tid, b = g>>9, n = g&511;
    float xv = red[0][tid] + red[1][tid] + b_out[0];
    xn[g] = xv;
    out[((size_t)b*FW + t)*Nn + n] = xv;
  }
}

extern "C" void kernel_launch(void* const* d_in, const int* in_sizes, int n_in,
                              void* d_out, int out_size, void* d_ws, size_t ws_size,
                              hipStream_t stream){
  const float* feature = (const float*)d_in[0];
  const float* pm25    = (const float*)d_in[1];
  const int*   eidx    = (const int*)d_in[2];
  const float* W_nb    = (const float*)d_in[3];
  const float* b_nb    = (const float*)d_in[4];
  const float* W_root  = (const float*)d_in[5];
  const float* W_ih    = (const float*)d_in[6];
  const float* W_hh    = (const float*)d_in[7];
  const float* b_ih    = (const float*)d_in[8];
  const float* b_hh    = (const float*)d_in[9];
  const float* W_out   = (const float*)d_in[10];
  const float* b_out   = (const float*)d_in[11];
  float* out = (float*)d_out;
  const int* src = eidx;
  const int* dst = eidx + NE;

  float* ws = (float*)d_ws;
  float* invdeg = ws;  ws += BN;
  float* xn     = ws;  ws += BN;
  float* SX     = ws;  ws += BN;
  float* sfeat  = ws;  ws += (size_t)FW*BN;
  float* rootf  = ws;  ws += (size_t)FW*BN;
  float* SF     = ws;  ws += (size_t)FW*BN;
  float* Wt_hh  = ws;  ws += 128*384;
  float* Wt_ih  = ws;  ws += 18*384;
  float* hbuf   = ws;  ws += (size_t)BN*Hh;

  hipMemsetAsync(invdeg, 0, BN*sizeof(float), stream);
  hipMemsetAsync(SF, 0, (size_t)FW*BN*sizeof(float), stream);
  hipMemsetAsync(hbuf, 0, (size_t)BN*Hh*sizeof(float), stream);

  k_deg<<<NE/256, 256, 0, stream>>>(dst, invdeg);
  k_invdeg<<<BN/256, 256, 0, stream>>>(invdeg);
  k_init_xn<<<BN/256, 256, 0, stream>>>(pm25, xn);
  k_transpose<<<(384*128 + 255)/256, 256, 0, stream>>>(W_ih, W_hh, Wt_ih, Wt_hh);
  k_sfeat<<<(FW*BN)/256, 256, 0, stream>>>(feature, W_nb, W_root, sfeat, rootf);
  k_aggF<<<NE/256, 256, 0, stream>>>(src, dst, sfeat, SF);

  for (int t = 0; t < FW; t++){
    hipMemsetAsync(SX, 0, BN*sizeof(float), stream);
    k_sx<<<NE/256, 256, 0, stream>>>(src, dst, xn, SX);
    k_gru<<<BN/GM, 128, 0, stream>>>(hbuf, xn, SX, SF + (size_t)t*BN, rootf + (size_t)t*BN,
                                     invdeg, feature, Wt_hh, Wt_ih, b_ih, b_hh,
                                     W_nb, b_nb, W_root, W_out, b_out, out, t);
  }
}